// Round 1
// baseline (6222.399 us; speedup 1.0000x reference)
//
#include <hip/hip_runtime.h>
#include <math.h>

// ---------------- problem constants ----------------
#define BB 16
#define CIN 15          // C*T
#define HW 384
#define E_NUM 3
#define GC 64           // gating / conv1 out channels
#define GH 192          // gating conv out spatial
#define PH 96           // pooled / expert spatial
#define HEAD_OC 384     // N_HEADS*HEAD_CONV
#define K7 49
#define K7C (CIN*K7)    // 735
#define OUT_ELEMS (BB*6*PH*PH)   // 884736

// ws layout (float offsets)
#define OFF_WT_G   0                         // [735][64]
#define OFF_WT_E1  47040                     // [3][735][64]
#define OFF_WT_H1  188160                    // [3][576][384]
#define OFF_FEAT   851712                    // [16][64]
#define OFF_IDX    852736                    // 16 ints
#define OFF_BUF    852800                    // pooled [16,64,96,96] then reused as Y1

// ---------------- K0: weight transpose prep ----------------
__global__ __launch_bounds__(256) void k_prep(
    const float* __restrict__ g_conv_w,   // [64][735]
    const float* __restrict__ e_conv1_w,  // [3][64][735]
    const float* __restrict__ e_head_w1,  // [3][384][576]
    float* __restrict__ ws)
{
  int i = blockIdx.x * 256 + threadIdx.x;
  int n0 = 47040, n1 = 141120, n2 = 663552;
  if (i < n0) {
    int k = i >> 6, oc = i & 63;
    ws[OFF_WT_G + i] = g_conv_w[oc * K7C + k];
  } else if (i < n0 + n1) {
    int j = i - n0;
    int e = j / 47040, r = j % 47040;
    int k = r >> 6, oc = r & 63;
    ws[OFF_WT_E1 + j] = e_conv1_w[(e * 64 + oc) * K7C + k];
  } else if (i < n0 + n1 + n2) {
    int j = i - n0 - n1;
    int e = j / 221184, r = j % 221184;
    int q = r / 384, oc2 = r % 384;
    ws[OFF_WT_H1 + j] = e_head_w1[(e * 384 + oc2) * 576 + q];
  }
}

// ---------------- K1: gating conv + BN + ReLU + maxpool (fused) ----------------
// grid (12,12,16) block 256. Each block: pooled 8x8 tile, all 64 oc (2 chunks of 32).
// conv tile needed: 17x17 at cy0 = 2*py0-1.
__global__ __launch_bounds__(256) void k_gate_conv_pool(
    const float* __restrict__ x,
    const float* __restrict__ wT,     // [735][64]
    const float* __restrict__ gamma, const float* __restrict__ beta,
    const float* __restrict__ mean,  const float* __restrict__ var,
    float* __restrict__ P)            // [16][64][96][96]
{
  int px0 = blockIdx.x * 8, py0 = blockIdx.y * 8, b = blockIdx.z;
  int t = threadIdx.x;
  __shared__ float patch[39 * 39];     // per-ic input patch
  __shared__ float pool[32 * 289];     // conv values for one oc chunk

  int p1 = t;
  int r1 = p1 / 17, c1 = p1 % 17;
  int p2 = t + 256;
  bool has2 = (p2 < 289);
  int r2 = has2 ? p2 / 17 : 0, c2 = has2 ? p2 % 17 : 0;

  int cy0 = 2 * py0 - 1, cx0 = 2 * px0 - 1;
  int iy0 = 2 * cy0 - 3, ix0 = 2 * cx0 - 3;   // 4*py0-5
  const float* xb = x + (size_t)b * CIN * HW * HW;

  for (int ocb = 0; ocb < 64; ocb += 32) {
    float acc[32], acc2[32];
#pragma unroll
    for (int j = 0; j < 32; ++j) { acc[j] = 0.f; acc2[j] = 0.f; }

    for (int ic = 0; ic < CIN; ++ic) {
      __syncthreads();
      const float* xc = xb + (size_t)ic * HW * HW;
      for (int i = t; i < 1521; i += 256) {
        int ry = i / 39, rx = i % 39;
        int iy = iy0 + ry, ix = ix0 + rx;
        float v = 0.f;
        if (iy >= 0 && iy < HW && ix >= 0 && ix < HW) v = xc[iy * HW + ix];
        patch[i] = v;
      }
      __syncthreads();
      const float* wic = wT + ic * K7 * 64 + ocb;
      for (int ky = 0; ky < 7; ++ky) {
        int ro1 = (2 * r1 + ky) * 39 + 2 * c1;
        int ro2 = (2 * r2 + ky) * 39 + 2 * c2;
#pragma unroll
        for (int kx = 0; kx < 7; ++kx) {
          float v1 = patch[ro1 + kx];
          float v2 = patch[ro2 + kx];
          const float* wk = wic + (ky * 7 + kx) * 64;
#pragma unroll
          for (int j = 0; j < 32; ++j) acc[j] = fmaf(v1, wk[j], acc[j]);
          if (has2) {
#pragma unroll
            for (int j = 0; j < 32; ++j) acc2[j] = fmaf(v2, wk[j], acc2[j]);
          }
        }
      }
    }
    __syncthreads();
    // BN + ReLU, store conv tile to LDS (OOB conv coords -> 0; safe since relu>=0)
#pragma unroll
    for (int j = 0; j < 32; ++j) {
      int oc = ocb + j;
      float inv = gamma[oc] * rsqrtf(var[oc] + 1e-5f);
      float sh = beta[oc] - mean[oc] * inv;
      {
        int cy = cy0 + r1, cx = cx0 + c1;
        float v = (cy >= 0 && cy < GH && cx >= 0 && cx < GH)
                    ? fmaxf(fmaf(acc[j], inv, sh), 0.f) : 0.f;
        pool[j * 289 + p1] = v;
      }
      if (has2) {
        int cy = cy0 + r2, cx = cx0 + c2;
        float v = (cy >= 0 && cy < GH && cx >= 0 && cx < GH)
                    ? fmaxf(fmaf(acc2[j], inv, sh), 0.f) : 0.f;
        pool[j * 289 + p2] = v;
      }
    }
    __syncthreads();
    // maxpool 3x3 s2 p1 over the LDS tile -> pooled 8x8 for 32 ocs
    for (int u = 0; u < 8; ++u) {
      int task = u * 256 + t;          // 0..2047
      int jl = task >> 6;              // 0..31
      int pix = task & 63;
      int py = pix >> 3, px = pix & 7;
      const float* pl = &pool[jl * 289];
      int rb = 2 * py, cb = 2 * px;
      float m = 0.f;
#pragma unroll
      for (int dy = 0; dy < 3; ++dy)
#pragma unroll
        for (int dx = 0; dx < 3; ++dx)
          m = fmaxf(m, pl[(rb + dy) * 17 + cb + dx]);
      int oc = ocb + jl;
      P[(((size_t)b * 64 + oc) * PH + (py0 + py)) * PH + (px0 + px)] = m;
    }
  }
}

// ---------------- K2: spatial mean -> feat[16][64] ----------------
__global__ __launch_bounds__(256) void k_feat(const float* __restrict__ P,
                                              float* __restrict__ feat)
{
  int bo = blockIdx.x;   // b*64+oc
  const float* p = P + (size_t)bo * (PH * PH);
  int t = threadIdx.x;
  float s = 0.f;
  for (int i = t; i < PH * PH; i += 256) s += p[i];
  __shared__ float red[256];
  red[t] = s;
  __syncthreads();
  for (int off = 128; off > 0; off >>= 1) {
    if (t < off) red[t] += red[t + off];
    __syncthreads();
  }
  if (t == 0) feat[bo] = red[0] * (1.f / (PH * PH));
}

// ---------------- K3: FC + argmax + aux loss ----------------
__global__ __launch_bounds__(64) void k_gate_fc(
    const float* __restrict__ feat, const float* __restrict__ fcw,
    const float* __restrict__ fcb, int* __restrict__ idxb,
    float* __restrict__ out_aux)
{
  __shared__ float sm[16][3];
  __shared__ int sidx[16];
  int t = threadIdx.x;
  if (t < 16) {
    float l[3];
#pragma unroll
    for (int e = 0; e < 3; ++e) {
      float s = fcb[e];
      for (int c = 0; c < 64; ++c) s = fmaf(feat[t * 64 + c], fcw[e * 64 + c], s);
      l[e] = s;
    }
    int best = 0;
    float bv = l[0];
    if (l[1] > bv) { bv = l[1]; best = 1; }
    if (l[2] > bv) { bv = l[2]; best = 2; }
    sidx[t] = best;
    idxb[t] = best;
    float mx = fmaxf(l[0], fmaxf(l[1], l[2]));
    float e0 = expf(l[0] - mx), e1 = expf(l[1] - mx), e2 = expf(l[2] - mx);
    float d = e0 + e1 + e2;
    sm[t][0] = e0 / d; sm[t][1] = e1 / d; sm[t][2] = e2 / d;
  }
  __syncthreads();
  if (t == 0) {
    float aux = 0.f;
    for (int e = 0; e < 3; ++e) {
      float cnt = 0.f, pr = 0.f;
      for (int b = 0; b < 16; ++b) {
        cnt += (sidx[b] == e) ? 1.f : 0.f;
        pr += sm[b][e];
      }
      aux += (cnt / 16.f) * (pr / 16.f);
    }
    *out_aux = 0.01f * aux * 3.f;
  }
}

// ---------------- K4: selected-expert conv1 7x7 s4 + bias + relu ----------------
// grid (6,6,16) block 256 (16x16 out tile), 64 accs/thread.
__global__ __launch_bounds__(256) void k_econv1(
    const float* __restrict__ x, const float* __restrict__ wTe1,
    const float* __restrict__ ebias, const int* __restrict__ idxb,
    float* __restrict__ Y)
{
  int b = blockIdx.z;
  int e = idxb[b];
  int ox0 = blockIdx.x * 16, oy0 = blockIdx.y * 16;
  int t = threadIdx.x;
  int ty = t >> 4, tx = t & 15;
  int iy0 = 4 * oy0 - 3, ix0 = 4 * ox0 - 3;
  __shared__ float patch[67 * 67];    // 4489
  const float* xb = x + (size_t)b * CIN * HW * HW;
  const float* wT = wTe1 + (size_t)e * K7C * 64;

  float acc[64];
#pragma unroll
  for (int j = 0; j < 64; ++j) acc[j] = 0.f;

  for (int ic = 0; ic < CIN; ++ic) {
    __syncthreads();
    const float* xc = xb + (size_t)ic * HW * HW;
    for (int i = t; i < 4489; i += 256) {
      int ry = i / 67, rx = i % 67;
      int iy = iy0 + ry, ix = ix0 + rx;
      float v = 0.f;
      if (iy >= 0 && iy < HW && ix >= 0 && ix < HW) v = xc[iy * HW + ix];
      patch[i] = v;
    }
    __syncthreads();
    const float* wic = wT + ic * K7 * 64;
    for (int ky = 0; ky < 7; ++ky) {
      int ro = (4 * ty + ky) * 67 + 4 * tx;
#pragma unroll
      for (int kx = 0; kx < 7; ++kx) {
        float v = patch[ro + kx];
        const float* wk = wic + (ky * 7 + kx) * 64;
#pragma unroll
        for (int j = 0; j < 64; ++j) acc[j] = fmaf(v, wk[j], acc[j]);
      }
    }
  }
  const float* bias = ebias + e * 64;
  int oy = oy0 + ty, ox = ox0 + tx;
#pragma unroll
  for (int j = 0; j < 64; ++j) {
    float v = fmaxf(acc[j] + bias[j], 0.f);
    Y[(((size_t)b * 64 + j) * PH + oy) * PH + ox] = v;
  }
}

// ---------------- K5: fused head conv1(3x3,64->384)+relu + grouped 1x1 -> out ----------------
// grid (12,12,16) block 256 (4 waves). 8x8 pixel tile; wave w handles oc2 [w*96,(w+1)*96).
__global__ __launch_bounds__(256) void k_head(
    const float* __restrict__ Y, const float* __restrict__ wTh1,
    const float* __restrict__ b1, const float* __restrict__ w2,
    const float* __restrict__ b2, const int* __restrict__ idxb,
    float* __restrict__ out)
{
  int b = blockIdx.z;
  int e = idxb[b];
  int px0 = blockIdx.x * 8, py0 = blockIdx.y * 8;
  int t = threadIdx.x;
  int wave = t >> 6, lane = t & 63;
  int py = lane >> 3, px = lane & 7;

  __shared__ float ldsY[64 * 100];    // [ic][10][10]
  __shared__ float red[4][64][6];

  for (int i = t; i < 6400; i += 256) {
    int ic = i / 100, rr = i % 100;
    int ry = rr / 10, rx = rr % 10;
    int gy = py0 - 1 + ry, gx = px0 - 1 + rx;
    float v = 0.f;
    if (gy >= 0 && gy < PH && gx >= 0 && gx < PH)
      v = Y[(((size_t)b * 64 + ic) * PH + gy) * PH + gx];
    ldsY[i] = v;
  }
#pragma unroll
  for (int c = 0; c < 6; ++c) red[wave][lane][c] = 0.f;
  __syncthreads();

  const float* wT = wTh1 + (size_t)e * 576 * 384;
  const float* bb1 = b1 + e * 384;
  const float* ww2 = w2 + e * 768;

  for (int sub = 0; sub < 3; ++sub) {
    int base = wave * 96 + sub * 32;   // 32-chunk never crosses a 128 group boundary
    float acc[32];
#pragma unroll
    for (int j = 0; j < 32; ++j) acc[j] = bb1[base + j];
    for (int q = 0; q < 576; ++q) {
      int ic = q / 9, kk = q % 9;
      int ky = kk / 3, kx = kk % 3;
      float v = ldsY[ic * 100 + (py + ky) * 10 + (px + kx)];
      const float* wk = wT + q * 384 + base;
#pragma unroll
      for (int j = 0; j < 32; ++j) acc[j] = fmaf(v, wk[j], acc[j]);
    }
    int g = base >> 7;
    int kb = base & 127;
    const float* w2a = ww2 + (2 * g) * 128 + kb;
    const float* w2b = w2a + 128;
    float pa = 0.f, pb = 0.f;
#pragma unroll
    for (int j = 0; j < 32; ++j) {
      float tv = fmaxf(acc[j], 0.f);
      pa = fmaf(tv, w2a[j], pa);
      pb = fmaf(tv, w2b[j], pb);
    }
    red[wave][lane][2 * g] += pa;
    red[wave][lane][2 * g + 1] += pb;
  }
  __syncthreads();
  if (wave == 0) {
#pragma unroll
    for (int c = 0; c < 6; ++c) {
      float s = red[0][lane][c] + red[1][lane][c] + red[2][lane][c] +
                red[3][lane][c] + b2[e * 6 + c];
      out[(((size_t)b * 6 + c) * PH + (py0 + py)) * PH + (px0 + px)] = s;
    }
  }
}

// ---------------- launch ----------------
extern "C" void kernel_launch(void* const* d_in, const int* in_sizes, int n_in,
                              void* d_out, int out_size, void* d_ws, size_t ws_size,
                              hipStream_t stream)
{
  const float* x         = (const float*)d_in[0];
  const float* g_conv_w  = (const float*)d_in[1];
  const float* g_bn_g    = (const float*)d_in[2];
  const float* g_bn_b    = (const float*)d_in[3];
  const float* g_bn_m    = (const float*)d_in[4];
  const float* g_bn_v    = (const float*)d_in[5];
  const float* g_fc_w    = (const float*)d_in[6];
  const float* g_fc_b    = (const float*)d_in[7];
  const float* e_conv1_w = (const float*)d_in[8];
  const float* e_conv1_b = (const float*)d_in[9];
  const float* e_head_w1 = (const float*)d_in[10];
  const float* e_head_b1 = (const float*)d_in[11];
  const float* e_head_w2 = (const float*)d_in[12];
  const float* e_head_b2 = (const float*)d_in[13];

  float* ws   = (float*)d_ws;
  float* wT_g  = ws + OFF_WT_G;
  float* wT_e1 = ws + OFF_WT_E1;
  float* wT_h1 = ws + OFF_WT_H1;
  float* feat  = ws + OFF_FEAT;
  int*   idxb  = (int*)(ws + OFF_IDX);
  float* buf   = ws + OFF_BUF;        // pooled, then reused as Y1 (same size)

  float* out = (float*)d_out;
  float* out_aux = out + OUT_ELEMS;

  hipLaunchKernelGGL(k_prep, dim3(3327), dim3(256), 0, stream,
                     g_conv_w, e_conv1_w, e_head_w1, ws);
  hipLaunchKernelGGL(k_gate_conv_pool, dim3(12, 12, 16), dim3(256), 0, stream,
                     x, wT_g, g_bn_g, g_bn_b, g_bn_m, g_bn_v, buf);
  hipLaunchKernelGGL(k_feat, dim3(1024), dim3(256), 0, stream, buf, feat);
  hipLaunchKernelGGL(k_gate_fc, dim3(1), dim3(64), 0, stream,
                     feat, g_fc_w, g_fc_b, idxb, out_aux);
  hipLaunchKernelGGL(k_econv1, dim3(6, 6, 16), dim3(256), 0, stream,
                     x, wT_e1, e_conv1_b, idxb, buf);
  hipLaunchKernelGGL(k_head, dim3(12, 12, 16), dim3(256), 0, stream,
                     buf, wT_h1, e_head_b1, e_head_w2, e_head_b2, idxb, out);
}

// Round 2
// 925.075 us; speedup vs baseline: 6.7264x; 6.7264x over previous
//
#include <hip/hip_runtime.h>
#include <math.h>

// ---------------- problem constants ----------------
#define BB 16
#define CIN 15
#define HW 384
#define XPL 147456              // 384*384
#define NX 35389440             // 16*15*384*384
#define PH 96
#define GW 192
#define Y1N 9437184             // 16*96*96*64
#define Y1PL 589824             // 96*96*64
#define OUT_ELEMS (BB*6*PH*PH)

// ws byte offsets
#define OFF_WG   0              // [64][960] bf16 (BN-folded)        122880 B
#define OFF_WE1  122880         // [3][64][960] bf16                 368640 B
#define OFF_WH   491520         // [3][384][576] bf16 (k=kk*64+ic)  1327104 B
#define OFF_WTG  1818624        // fallback fp32 [735][64]           188160 B
#define OFF_GSH  2006784        // fp32 [64]                            256 B
#define OFF_FEAT 2007040        // fp32 [16][64]                       4096 B
#define OFF_IDX  2011136        // int  [16]                             64 B
#define OFF_BIG  2097152        // Cbuf (fast) / P (fallback) / Y1 alias
#define FAST_NEED (2097152ull + 75497472ull)

typedef __attribute__((ext_vector_type(8))) short short8;
typedef __attribute__((ext_vector_type(4))) float floatx4;
typedef __attribute__((ext_vector_type(4))) unsigned int uintx4;
typedef __attribute__((ext_vector_type(2))) unsigned int uintx2;

__device__ __forceinline__ unsigned bf16rne(float f) {
  unsigned u = __float_as_uint(f);
  unsigned r = ((u >> 16) & 1u) + 0x7FFFu;
  return (u + r) >> 16;
}
__device__ __forceinline__ float bf2f(unsigned short s) {
  return __uint_as_float(((unsigned)s) << 16);
}

// ---------------- K0: weight prep ----------------
// Wg: [oc][k960], k = ic*64+ky*8+kx, BN-folded. We1: [e][oc][k960].
// Wh: [e][oc][k576], k = (ky*3+kx)*64+ic. wTg: fallback fp32 [735][64]. gsh: BN shift.
__global__ __launch_bounds__(256) void k_prep(
    const float* __restrict__ g_conv_w, const float* __restrict__ e_conv1_w,
    const float* __restrict__ e_head_w1,
    const float* __restrict__ gamma, const float* __restrict__ var,
    const float* __restrict__ beta,  const float* __restrict__ mean,
    unsigned char* __restrict__ wsb)
{
  int i = blockIdx.x * 256 + threadIdx.x;
  unsigned short* Wg  = (unsigned short*)(wsb + OFF_WG);
  unsigned short* We1 = (unsigned short*)(wsb + OFF_WE1);
  unsigned short* Wh  = (unsigned short*)(wsb + OFF_WH);
  float* wTg = (float*)(wsb + OFF_WTG);
  float* gsh = (float*)(wsb + OFF_GSH);
  if (i < 61440) {
    int oc = i / 960, k = i % 960;
    int ic = k >> 6, rem = k & 63, ky = rem >> 3, kx = rem & 7;
    float v = 0.f;
    if (ky < 7 && kx < 7) v = g_conv_w[oc * 735 + ic * 49 + ky * 7 + kx];
    float inv = gamma[oc] * rsqrtf(var[oc] + 1e-5f);
    Wg[i] = (unsigned short)bf16rne(v * inv);
  } else if (i < 245760) {
    int j = i - 61440;
    int e = j / 61440, r = j % 61440;
    int oc = r / 960, k = r % 960;
    int ic = k >> 6, rem = k & 63, ky = rem >> 3, kx = rem & 7;
    float v = 0.f;
    if (ky < 7 && kx < 7) v = e_conv1_w[(e * 64 + oc) * 735 + ic * 49 + ky * 7 + kx];
    We1[j] = (unsigned short)bf16rne(v);
  } else if (i < 909312) {
    int j = i - 245760;
    int e = j / 221184, r = j % 221184;
    int oc = r / 576, k = r % 576;
    int kk = k >> 6, ic = k & 63;
    float v = e_head_w1[((e * 384 + oc) * 64 + ic) * 9 + kk];
    Wh[j] = (unsigned short)bf16rne(v);
  } else if (i < 956352) {
    int j = i - 909312;
    int k = j >> 6, oc = j & 63;
    wTg[j] = g_conv_w[oc * 735 + k];
  } else if (i < 956416) {
    int oc = i - 956352;
    float inv = gamma[oc] * rsqrtf(var[oc] + 1e-5f);
    gsh[oc] = beta[oc] - mean[oc] * inv;
  }
}

// ---------------- MFMA 7x7 conv (gating S=2 / expert1 S=4) ----------------
// Block: 16x16 out tile, 4 waves; wave w owns rows 4w..4w+3 (4 n-tiles of 16 px),
// all 64 oc (4 m-tiles). K = 15 ic * 64 (ky,kx padded 7->8). No LDS in K-loop:
// A-frags = b128 from W[oc][k] bf16; B-frags = in-register im2col from x rows.
template<int S, int OW, bool EXP>
__global__ __launch_bounds__(256) void k_conv7(
    const float* __restrict__ x, const unsigned short* __restrict__ Wp,
    const float* __restrict__ biasp, const int* __restrict__ idxb,
    unsigned short* __restrict__ Obuf)
{
  const int t = threadIdx.x, w = t >> 6, lane = t & 63, q = lane >> 4, ln = lane & 15;
  const int b = blockIdx.z;
  const int e = EXP ? idxb[b] : 0;
  const unsigned short* W = Wp + e * 61440;
  const float* bs = biasp + e * 64;
  const int px0 = blockIdx.x * 16, py0 = blockIdx.y * 16;
  const int px = px0 + ln;

  const int c0 = S * px - 3;          // col of element t=0
  const int r0 = c0 & 3;
  const int acol = c0 - r0;           // 16B-aligned col base
  unsigned pm[4];
#pragma unroll
  for (int j = 0; j < 4; ++j) {
    int t0 = 2 * j, t1 = 2 * j + 1;
    unsigned m0 = (c0 + t0 >= 0 && c0 + t0 < HW) ? 0x0000FFFFu : 0u;
    unsigned m1 = (c0 + t1 >= 0 && c0 + t1 < HW) ? 0xFFFF0000u : 0u;
    pm[j] = m0 | m1;
  }
  const bool sel3 = (r0 == 3);        // only hits for S=2

  int syq[4];
#pragma unroll
  for (int nt = 0; nt < 4; ++nt) {
    int py = py0 + w * 4 + nt;
    syq[nt] = S * py + q - 3;
  }
  int aoff[4];
#pragma unroll
  for (int mt = 0; mt < 4; ++mt) aoff[mt] = (mt * 16 + ln) * 960 + q * 8;
  const int xbase = b * CIN * XPL;

  floatx4 acc[4][4];
#pragma unroll
  for (int mt = 0; mt < 4; ++mt)
#pragma unroll
    for (int nt = 0; nt < 4; ++nt) acc[mt][nt] = 0.f;

#pragma unroll 3
  for (int ic = 0; ic < CIN; ++ic) {
    const int icb = xbase + ic * XPL;
#pragma unroll
    for (int h = 0; h < 2; ++h) {
      short8 bf[4];
#pragma unroll
      for (int nt = 0; nt < 4; ++nt) {
        int iy = syq[nt] + 4 * h;                        // S*py + ky - 3, ky = 4h+q
        bool rv = (iy >= 0) && (iy < HW) && ((4 * h + q) < 7);
        int a0 = icb + iy * HW + acol;
        a0 = max(a0, 0); a0 = min(a0, NX - 12);
        const float* fp = x + a0;
        floatx4 fA = *(const floatx4*)(fp);
        floatx4 fB = *(const floatx4*)(fp + 4);
        floatx4 fC = *(const floatx4*)(fp + 8);
        float g[8];
        if (S == 4) {
          g[0] = fA.y; g[1] = fA.z; g[2] = fA.w; g[3] = fB.x;
          g[4] = fB.y; g[5] = fB.z; g[6] = fB.w; g[7] = fC.x;
        } else {
          g[0] = sel3 ? fA.w : fA.y;  g[1] = sel3 ? fB.x : fA.z;
          g[2] = sel3 ? fB.y : fA.w;  g[3] = sel3 ? fB.z : fB.x;
          g[4] = sel3 ? fB.w : fB.y;  g[5] = sel3 ? fC.x : fB.z;
          g[6] = sel3 ? fC.y : fB.w;  g[7] = sel3 ? fC.z : fC.x;
        }
        union { unsigned u[4]; short8 s; } cv;
#pragma unroll
        for (int j = 0; j < 4; ++j) {
          unsigned p = __builtin_amdgcn_perm(__float_as_uint(g[2 * j + 1]),
                                             __float_as_uint(g[2 * j]), 0x07060302u);
          p &= pm[j];
          cv.u[j] = rv ? p : 0u;
        }
        bf[nt] = cv.s;
      }
      const int kOff = ic * 64 + h * 32;
#pragma unroll
      for (int mt = 0; mt < 4; ++mt) {
        short8 af = *(const short8*)(W + aoff[mt] + kOff);
#pragma unroll
        for (int nt = 0; nt < 4; ++nt)
          acc[mt][nt] = __builtin_amdgcn_mfma_f32_16x16x32_bf16(af, bf[nt], acc[mt][nt], 0, 0, 0);
      }
    }
  }

  // epilogue: bias + relu -> bf16 NHWC
#pragma unroll
  for (int nt = 0; nt < 4; ++nt) {
    int py = py0 + w * 4 + nt;
    size_t rowo = (((size_t)b * OW + py) * OW + px) * 64;
#pragma unroll
    for (int mt = 0; mt < 4; ++mt) {
      int ocb = mt * 16 + q * 4;
      float v0 = fmaxf(acc[mt][nt][0] + bs[ocb + 0], 0.f);
      float v1 = fmaxf(acc[mt][nt][1] + bs[ocb + 1], 0.f);
      float v2 = fmaxf(acc[mt][nt][2] + bs[ocb + 2], 0.f);
      float v3 = fmaxf(acc[mt][nt][3] + bs[ocb + 3], 0.f);
      uintx2 pr;
      pr.x = (bf16rne(v1) << 16) | bf16rne(v0);
      pr.y = (bf16rne(v3) << 16) | bf16rne(v2);
      *(uintx2*)(Obuf + rowo + ocb) = pr;
    }
  }
}

// ---------------- pool(3x3 s2 p1) + mean partial over Cbuf NHWC bf16 ----------------
__global__ __launch_bounds__(256) void k_pool(const unsigned short* __restrict__ Cb,
                                              float* __restrict__ feat)
{
  const int py = blockIdx.x, b = blockIdx.y;
  const int t = threadIdx.x, oc = t & 63, strip = t >> 6;
  const unsigned short* base = Cb + (size_t)b * GW * GW * 64 + oc;
  float sum = 0.f;
  for (int px = strip * 24; px < strip * 24 + 24; ++px) {
    float m = 0.f;
#pragma unroll
    for (int dy = 0; dy < 3; ++dy) {
      int row = 2 * py - 1 + dy;
      if (row < 0 || row >= GW) continue;
#pragma unroll
      for (int dx = 0; dx < 3; ++dx) {
        int col = 2 * px - 1 + dx;
        if (col < 0 || col >= GW) continue;
        m = fmaxf(m, bf2f(base[((size_t)row * GW + col) * 64]));
      }
    }
    sum += m;
  }
  __shared__ float red[4][64];
  red[strip][oc] = sum;
  __syncthreads();
  if (t < 64) {
    float s = red[0][oc] + red[1][oc] + red[2][oc] + red[3][oc];
    atomicAdd(&feat[b * 64 + oc], s);
  }
}

// ---------------- FC + argmax + aux (feat holds SUMS; divide here) ----------------
__global__ __launch_bounds__(64) void k_gate_fc(
    const float* __restrict__ feat, const float* __restrict__ fcw,
    const float* __restrict__ fcb, int* __restrict__ idxb,
    float* __restrict__ out_aux)
{
  __shared__ float sm[16][3];
  __shared__ int sidx[16];
  int t = threadIdx.x;
  if (t < 16) {
    float l[3];
#pragma unroll
    for (int e = 0; e < 3; ++e) {
      float s = fcb[e];
      for (int c = 0; c < 64; ++c)
        s = fmaf(feat[t * 64 + c] * (1.f / 9216.f), fcw[e * 64 + c], s);
      l[e] = s;
    }
    int best = 0; float bv = l[0];
    if (l[1] > bv) { bv = l[1]; best = 1; }
    if (l[2] > bv) { bv = l[2]; best = 2; }
    sidx[t] = best; idxb[t] = best;
    float mx = fmaxf(l[0], fmaxf(l[1], l[2]));
    float e0 = expf(l[0] - mx), e1 = expf(l[1] - mx), e2 = expf(l[2] - mx);
    float d = e0 + e1 + e2;
    sm[t][0] = e0 / d; sm[t][1] = e1 / d; sm[t][2] = e2 / d;
  }
  __syncthreads();
  if (t == 0) {
    float aux = 0.f;
    for (int e = 0; e < 3; ++e) {
      float cnt = 0.f, pr = 0.f;
      for (int b = 0; b < 16; ++b) { cnt += (sidx[b] == e) ? 1.f : 0.f; pr += sm[b][e]; }
      aux += (cnt / 16.f) * (pr / 16.f);
    }
    *out_aux = 0.01f * aux * 3.f;
  }
}

// ---------------- head: 3x3 64->384 MFMA + fused grouped 1x1 -> out ----------------
// Block: 16x4 px tile; waves own 96-oc chunks (6 m-tiles); B-frags = b128 from NHWC Y1.
__global__ __launch_bounds__(256) void k_headm(
    const unsigned short* __restrict__ Y1, const unsigned short* __restrict__ Whp,
    const float* __restrict__ b1, const float* __restrict__ w2,
    const float* __restrict__ b2, const int* __restrict__ idxb,
    float* __restrict__ out)
{
  const int t = threadIdx.x, w = t >> 6, lane = t & 63, q = lane >> 4, ln = lane & 15;
  const int b = blockIdx.z, px0 = blockIdx.x * 16, py0 = blockIdx.y * 4;
  const int e = idxb[b];
  const unsigned short* W = Whp + e * 221184;
  const int px = px0 + ln;

  int aoff[6];
#pragma unroll
  for (int mt = 0; mt < 6; ++mt) aoff[mt] = (w * 96 + mt * 16 + ln) * 576 + q * 8;

  int bbase[4];
  bool vy[4][3];
#pragma unroll
  for (int nt = 0; nt < 4; ++nt) {
    int py = py0 + nt;
    bbase[nt] = b * Y1PL + (((py - 1) * PH) + (px - 1)) * 64 + q * 8;
#pragma unroll
    for (int ky = 0; ky < 3; ++ky) vy[nt][ky] = (py + ky - 1 >= 0) && (py + ky - 1 < PH);
  }
  bool vx[3];
#pragma unroll
  for (int kx = 0; kx < 3; ++kx) vx[kx] = (px + kx - 1 >= 0) && (px + kx - 1 < PH);

  floatx4 acc[6][4];
#pragma unroll
  for (int mt = 0; mt < 6; ++mt)
#pragma unroll
    for (int nt = 0; nt < 4; ++nt) acc[mt][nt] = 0.f;

#pragma unroll
  for (int kk = 0; kk < 9; ++kk) {
    const int ky = kk / 3, kx = kk % 3;
#pragma unroll
    for (int ih = 0; ih < 2; ++ih) {
      const int stepc = (ky * PH + kx) * 64 + ih * 32;
      short8 bf[4];
#pragma unroll
      for (int nt = 0; nt < 4; ++nt) {
        int addr = bbase[nt] + stepc;
        addr = max(addr, 0); addr = min(addr, Y1N - 8);
        union { uintx4 u; short8 s; } cv;
        cv.u = *(const uintx4*)(Y1 + addr);
        if (!(vy[nt][ky] && vx[kx])) cv.u = 0u;
        bf[nt] = cv.s;
      }
      const int kOff = kk * 64 + ih * 32;
#pragma unroll
      for (int mt = 0; mt < 6; ++mt) {
        short8 af = *(const short8*)(W + aoff[mt] + kOff);
#pragma unroll
        for (int nt = 0; nt < 4; ++nt)
          acc[mt][nt] = __builtin_amdgcn_mfma_f32_16x16x32_bf16(af, bf[nt], acc[mt][nt], 0, 0, 0);
      }
    }
  }

  // fused 1x1 grouped conv epilogue
  __shared__ float sred[4][4][16][6];
#pragma unroll
  for (int nt = 0; nt < 4; ++nt) {
    float part[6] = {0.f, 0.f, 0.f, 0.f, 0.f, 0.f};
#pragma unroll
    for (int mt = 0; mt < 6; ++mt) {
      int ocb = w * 96 + mt * 16 + q * 4;
#pragma unroll
      for (int r = 0; r < 4; ++r) {
        int oc = ocb + r;
        float y = fmaxf(acc[mt][nt][r] + b1[e * 384 + oc], 0.f);
        int g = oc >> 7, kb = oc & 127;
        part[2 * g]     += y * w2[(e * 6 + 2 * g) * 128 + kb];
        part[2 * g + 1] += y * w2[(e * 6 + 2 * g + 1) * 128 + kb];
      }
    }
#pragma unroll
    for (int c = 0; c < 6; ++c) {
      part[c] += __shfl_down(part[c], 32);
      part[c] += __shfl_down(part[c], 16);
    }
    if (q == 0) {
#pragma unroll
      for (int c = 0; c < 6; ++c) sred[nt][w][ln][c] = part[c];
    }
  }
  __syncthreads();
  for (int i = t; i < 384; i += 256) {
    int pix = i / 6, c = i % 6;
    int nt = pix >> 4, pl = pix & 15;
    float s = sred[nt][0][pl][c] + sred[nt][1][pl][c] + sred[nt][2][pl][c] +
              sred[nt][3][pl][c] + b2[e * 6 + c];
    out[(((size_t)(b * 6 + c)) * PH + (py0 + nt)) * PH + (px0 + pl)] = s;
  }
}

// ================= FALLBACK (small ws): round-1 fp32 gating =================
__global__ __launch_bounds__(256) void k_gate_conv_pool(
    const float* __restrict__ x, const float* __restrict__ wT,
    const float* __restrict__ gamma, const float* __restrict__ beta,
    const float* __restrict__ mean,  const float* __restrict__ var,
    float* __restrict__ P)
{
  int px0 = blockIdx.x * 8, py0 = blockIdx.y * 8, b = blockIdx.z;
  int t = threadIdx.x;
  __shared__ float patch[39 * 39];
  __shared__ float pool[32 * 289];
  int p1 = t, r1 = p1 / 17, c1 = p1 % 17;
  int p2 = t + 256;
  bool has2 = (p2 < 289);
  int r2 = has2 ? p2 / 17 : 0, c2 = has2 ? p2 % 17 : 0;
  int cy0 = 2 * py0 - 1, cx0 = 2 * px0 - 1;
  int iy0 = 2 * cy0 - 3, ix0 = 2 * cx0 - 3;
  const float* xb = x + (size_t)b * CIN * HW * HW;
  for (int ocb = 0; ocb < 64; ocb += 32) {
    float acc[32], acc2[32];
#pragma unroll
    for (int j = 0; j < 32; ++j) { acc[j] = 0.f; acc2[j] = 0.f; }
    for (int ic = 0; ic < CIN; ++ic) {
      __syncthreads();
      const float* xc = xb + (size_t)ic * HW * HW;
      for (int i = t; i < 1521; i += 256) {
        int ry = i / 39, rx = i % 39;
        int iy = iy0 + ry, ix = ix0 + rx;
        float v = 0.f;
        if (iy >= 0 && iy < HW && ix >= 0 && ix < HW) v = xc[iy * HW + ix];
        patch[i] = v;
      }
      __syncthreads();
      const float* wic = wT + ic * 49 * 64 + ocb;
      for (int ky = 0; ky < 7; ++ky) {
        int ro1 = (2 * r1 + ky) * 39 + 2 * c1;
        int ro2 = (2 * r2 + ky) * 39 + 2 * c2;
#pragma unroll
        for (int kx = 0; kx < 7; ++kx) {
          float v1 = patch[ro1 + kx];
          float v2 = patch[ro2 + kx];
          const float* wk = wic + (ky * 7 + kx) * 64;
#pragma unroll
          for (int j = 0; j < 32; ++j) acc[j] = fmaf(v1, wk[j], acc[j]);
          if (has2) {
#pragma unroll
            for (int j = 0; j < 32; ++j) acc2[j] = fmaf(v2, wk[j], acc2[j]);
          }
        }
      }
    }
    __syncthreads();
#pragma unroll
    for (int j = 0; j < 32; ++j) {
      int oc = ocb + j;
      float inv = gamma[oc] * rsqrtf(var[oc] + 1e-5f);
      float sh = beta[oc] - mean[oc] * inv;
      {
        int cy = cy0 + r1, cx = cx0 + c1;
        float v = (cy >= 0 && cy < GW && cx >= 0 && cx < GW)
                    ? fmaxf(fmaf(acc[j], inv, sh), 0.f) : 0.f;
        pool[j * 289 + p1] = v;
      }
      if (has2) {
        int cy = cy0 + r2, cx = cx0 + c2;
        float v = (cy >= 0 && cy < GW && cx >= 0 && cx < GW)
                    ? fmaxf(fmaf(acc2[j], inv, sh), 0.f) : 0.f;
        pool[j * 289 + p2] = v;
      }
    }
    __syncthreads();
    for (int u = 0; u < 8; ++u) {
      int task = u * 256 + t;
      int jl = task >> 6, pix = task & 63;
      int py = pix >> 3, px = pix & 7;
      const float* pl = &pool[jl * 289];
      int rb = 2 * py, cb = 2 * px;
      float m = 0.f;
#pragma unroll
      for (int dy = 0; dy < 3; ++dy)
#pragma unroll
        for (int dx = 0; dx < 3; ++dx)
          m = fmaxf(m, pl[(rb + dy) * 17 + cb + dx]);
      int oc = ocb + jl;
      P[(((size_t)b * 64 + oc) * PH + (py0 + py)) * PH + (px0 + px)] = m;
    }
  }
}

__global__ __launch_bounds__(256) void k_feat(const float* __restrict__ P,
                                              float* __restrict__ feat)
{
  int bo = blockIdx.x;
  const float* p = P + (size_t)bo * (PH * PH);
  int t = threadIdx.x;
  float s = 0.f;
  for (int i = t; i < PH * PH; i += 256) s += p[i];
  __shared__ float red[256];
  red[t] = s;
  __syncthreads();
  for (int off = 128; off > 0; off >>= 1) {
    if (t < off) red[t] += red[t + off];
    __syncthreads();
  }
  if (t == 0) feat[bo] = red[0];   // SUM (fc divides)
}

// ---------------- launch ----------------
extern "C" void kernel_launch(void* const* d_in, const int* in_sizes, int n_in,
                              void* d_out, int out_size, void* d_ws, size_t ws_size,
                              hipStream_t stream)
{
  const float* x         = (const float*)d_in[0];
  const float* g_conv_w  = (const float*)d_in[1];
  const float* g_bn_g    = (const float*)d_in[2];
  const float* g_bn_b    = (const float*)d_in[3];
  const float* g_bn_m    = (const float*)d_in[4];
  const float* g_bn_v    = (const float*)d_in[5];
  const float* g_fc_w    = (const float*)d_in[6];
  const float* g_fc_b    = (const float*)d_in[7];
  const float* e_conv1_b = (const float*)d_in[9];
  const float* e_head_b1 = (const float*)d_in[11];
  const float* e_head_w2 = (const float*)d_in[12];
  const float* e_head_b2 = (const float*)d_in[13];

  unsigned char* wsb = (unsigned char*)d_ws;
  unsigned short* Wg  = (unsigned short*)(wsb + OFF_WG);
  unsigned short* We1 = (unsigned short*)(wsb + OFF_WE1);
  unsigned short* Wh  = (unsigned short*)(wsb + OFF_WH);
  float* wTg  = (float*)(wsb + OFF_WTG);
  float* gsh  = (float*)(wsb + OFF_GSH);
  float* feat = (float*)(wsb + OFF_FEAT);
  int*   idxb = (int*)(wsb + OFF_IDX);
  unsigned short* bigbf = (unsigned short*)(wsb + OFF_BIG);  // Cbuf / Y1
  float* bigf = (float*)(wsb + OFF_BIG);                     // P (fallback)

  float* out = (float*)d_out;
  float* out_aux = out + OUT_ELEMS;
  const bool fast = (ws_size >= (size_t)FAST_NEED);

  hipLaunchKernelGGL(k_prep, dim3(3736), dim3(256), 0, stream,
                     g_conv_w, (const float*)d_in[8], (const float*)d_in[10],
                     g_bn_g, g_bn_v, g_bn_b, g_bn_m, wsb);

  if (fast) {
    hipMemsetAsync(feat, 0, 16 * 64 * sizeof(float), stream);
    hipLaunchKernelGGL((k_conv7<2, GW, false>), dim3(12, 12, 16), dim3(256), 0, stream,
                       x, Wg, gsh, idxb, bigbf);
    hipLaunchKernelGGL(k_pool, dim3(96, 16), dim3(256), 0, stream, bigbf, feat);
  } else {
    hipLaunchKernelGGL(k_gate_conv_pool, dim3(12, 12, 16), dim3(256), 0, stream,
                       x, wTg, g_bn_g, g_bn_b, g_bn_m, g_bn_v, bigf);
    hipLaunchKernelGGL(k_feat, dim3(1024), dim3(256), 0, stream, bigf, feat);
  }
  hipLaunchKernelGGL(k_gate_fc, dim3(1), dim3(64), 0, stream,
                     feat, g_fc_w, g_fc_b, idxb, out_aux);
  // expert conv1 -> Y1 (NHWC bf16), overlays Cbuf/P (both already consumed)
  hipLaunchKernelGGL((k_conv7<4, PH, true>), dim3(6, 6, 16), dim3(256), 0, stream,
                     x, We1, e_conv1_b, idxb, bigbf);
  hipLaunchKernelGGL(k_headm, dim3(6, 24, 16), dim3(256), 0, stream,
                     bigbf, Wh, e_head_b1, e_head_w2, e_head_b2, idxb, out);
}